// Round 4
// baseline (905.247 us; speedup 1.0000x reference)
//
#include <hip/hip_runtime.h>
#include <cstdint>
#include <cstddef>

// Problem constants (B=2048, H=4096, K=4)
#define HD   4096
#define BSZ  2048

// ---------------------------------------------------------------------------
// R5: same 8-phase schedule as R4 (verified), minus codegen overhead.
// R4 post-mortem: 5475 cyc/tile vs m201's 3297 at identical per-block work;
// VALUBusy 23% (~1276 cyc/tile) = addressing rematerialization (runtime K/N
// force v_mad_u64 chains; VGPR at the 256 cap; per-phase runtime branches).
// Changes: (1) constexpr K/N -> literal staging offsets; (2) last-iteration
// peel -> branchless steady-state loop; (3) smA/smB[buf][half] split so buf
// select is a ds_read offset: immediate; (4) lgkmcnt(8) pre-wait in 12-read
// phases (m201 template option); (5) XCD swizzle by bx-columns (24MB/XCD
// footprint vs 66MB); (6) merged cvt kernel (1 launch vs 4).
// ---------------------------------------------------------------------------
constexpr int BM = 128, BN = 128, BKT = 64;

typedef __bf16 bf16x8 __attribute__((ext_vector_type(8)));
typedef float  f32x4  __attribute__((ext_vector_type(4)));

__device__ __forceinline__ unsigned short f2bf(float f) {
  unsigned u = __float_as_uint(f);
  u += 0x7fffu + ((u >> 16) & 1u);   // RNE
  return (unsigned short)(u >> 16);
}
__device__ __forceinline__ float bf2f(unsigned short s) {
  return __uint_as_float(((unsigned)s) << 16);
}

#define AS1(p) ((__attribute__((address_space(1))) void*)(void*)(p))
#define AS3(p) ((__attribute__((address_space(3))) void*)(p))

// ---------------------------------------------------------------- converts
// One launch for all 4 conversions; every region size divisible by 256
// float4s -> branches are block-uniform.
__global__ void cvt_all(const float4* __restrict__ x,  const float4* __restrict__ wf,
                        const float4* __restrict__ wg, const float4* __restrict__ wo,
                        ushort4* __restrict__ xb,  ushort4* __restrict__ wfb,
                        ushort4* __restrict__ wgb, ushort4* __restrict__ wob) {
  constexpr int NX = BSZ * HD / 4;         // 2,097,152
  constexpr int NW = 2 * HD * HD / 4;      // 8,388,608
  constexpr int NO = HD * HD / 4;          // 4,194,304
  int i = blockIdx.x * 256 + threadIdx.x;
  const float4* s; ushort4* d; int o;
  if (i < NX)               { s = x;  d = xb;  o = i; }
  else if (i < NX + NW)     { s = wf; d = wfb; o = i - NX; }
  else if (i < NX + 2 * NW) { s = wg; d = wgb; o = i - (NX + NW); }
  else                      { s = wo; d = wob; o = i - (NX + 2 * NW); }
  float4 v = s[o];
  ushort4 r;
  r.x = f2bf(v.x); r.y = f2bf(v.y); r.z = f2bf(v.z); r.w = f2bf(v.w);
  d[o] = r;
  (void)NO;
}

// ---------------------------------------------------------------- 128^2 GEMM
// (GEMM3 only; dims now compile-time)
template <int MODE, int NN, int KK>
__global__ __launch_bounds__(256) void gemm_bt(
    const unsigned short* __restrict__ A, const unsigned short* __restrict__ Bw,
    float* __restrict__ outf, unsigned short* __restrict__ gate_bf,
    float* __restrict__ xrec) {
  __shared__ unsigned short smA[BM * BKT];
  __shared__ unsigned short smB[BN * BKT];
  const int tid  = threadIdx.x;
  const int wid  = tid >> 6;
  const int lane = tid & 63;
  const int wm = wid >> 1, wn = wid & 1;
  const int l16 = lane & 15, q = lane >> 4;
  const int bx = blockIdx.x, by = blockIdx.y;
  const int srow = tid >> 3;
  const int scol = (((tid & 7) ^ ((tid >> 3) & 7)) * 8);
  const unsigned short* Ab = A + (size_t)(by * BM) * KK + scol;
  const unsigned short* Bb = Bw + (size_t)(bx * BN) * KK + scol;
  const int ldsbase = (wid * 8) * BKT;
  f32x4 acc[4][4] = {};

  for (int kt = 0; kt < KK; kt += BKT) {
#pragma unroll
    for (int i = 0; i < 4; ++i) {
      __builtin_amdgcn_global_load_lds(AS1(Ab + (size_t)(i * 32 + srow) * KK + kt),
                                       AS3(smA + i * 32 * BKT + ldsbase), 16, 0, 0);
      __builtin_amdgcn_global_load_lds(AS1(Bb + (size_t)(i * 32 + srow) * KK + kt),
                                       AS3(smB + i * 32 * BKT + ldsbase), 16, 0, 0);
    }
    __syncthreads();
#pragma unroll
    for (int kk = 0; kk < BKT; kk += 32) {
      bf16x8 af[4], bfr[4];
#pragma unroll
      for (int i = 0; i < 4; ++i) {
        const int ar = wm * 64 + i * 16 + l16;
        af[i]  = *(const bf16x8*)(smA + ar * BKT + ((((kk >> 3) + q) ^ (ar & 7)) * 8));
      }
#pragma unroll
      for (int j = 0; j < 4; ++j) {
        const int br = wn * 64 + j * 16 + l16;
        bfr[j] = *(const bf16x8*)(smB + br * BKT + ((((kk >> 3) + q) ^ (br & 7)) * 8));
      }
#pragma unroll
      for (int i = 0; i < 4; ++i)
#pragma unroll
        for (int j = 0; j < 4; ++j)
          acc[i][j] = __builtin_amdgcn_mfma_f32_16x16x32_bf16(af[i], bfr[j], acc[i][j], 0, 0, 0);
    }
    __syncthreads();
  }

  const int gm0 = by * BM + wm * 64 + q * 4;
  const int gn0 = bx * BN + wn * 64 + l16;
#pragma unroll
  for (int i = 0; i < 4; ++i) {
#pragma unroll
    for (int j = 0; j < 4; ++j) {
      const int n = gn0 + j * 16;
#pragma unroll
      for (int r = 0; r < 4; ++r) {
        const int m = gm0 + i * 16 + r;
        float v = acc[i][j][r];
        if (MODE == 0) {
          outf[(size_t)m * NN + n] = v;
        } else if (MODE == 2) {
          float s = 1.0f / (1.0f + expf(-v));
          gate_bf[(size_t)m * NN + n] = f2bf(s);
        } else {
          if (n < HD) {
            float g = 0.5f * v * (1.0f + erff(v * 0.70710678118654752f));
            gate_bf[(size_t)m * HD + n] = f2bf(g);
          } else {
            xrec[(size_t)m * HD + (n - HD)] = v;
          }
        }
      }
    }
  }
}

// ---------------------------------------------------------------- 256^2 GEMM
// K is compile-time (HD): staging offsets fold to literals.
__device__ __forceinline__ void stage_half4(const unsigned short* src_rc,
                                            int h, int t,
                                            unsigned short* region, int wid) {
#pragma unroll
  for (int i = 0; i < 2; ++i)
    __builtin_amdgcn_global_load_lds(
        AS1(src_rc + (size_t)(h * 128 + i * 64) * HD + t * 64),
        AS3(region + wid * 8 * 64 + i * 64 * 64), 16, 0, 0);
}

// Schedule identical to R4 (verified ledger in that round's comments):
// per 2-tile iteration, 8 phases; vmcnt(6) at P4/P8 retires exactly the
// tile about to be consumed; entry invariant = next-odd-tile {A0,B0,B1}
// in flight. Last iteration peeled with D2=D3=false -> vmcnt(0).
__global__ __launch_bounds__(512, 2) void gemm256_k(
    const unsigned short* __restrict__ A, const unsigned short* __restrict__ Bw,
    unsigned short* __restrict__ gate_bf, float* __restrict__ xrec,
    const int MODE) {
  // split A/B so [buf][half] select is a 16-bit ds offset immediate
  __shared__ __align__(16) unsigned short smA[2][2][8192];
  __shared__ __align__(16) unsigned short smB[2][2][8192];
  const int tid  = threadIdx.x;
  const int wid  = tid >> 6;
  const int lane = tid & 63;
  const int wm = wid >> 2, wn = wid & 3;
  const int l16 = lane & 15, q = lane >> 4;
  constexpr int NN = 2 * HD;   // output ld
  constexpr int NT = HD / 64;  // 64 K-tiles

  // XCD swizzle, bx-column-chunked: XCD x owns bx in [x*4, x*4+4), all by.
  // Footprint/XCD = 4 B-panels (8MB) + A (16MB) = 24MB (vs 66MB row-chunked).
  // Bijective for grid 32x8 = 256.
  const int lin = blockIdx.y * 32 + blockIdx.x;
  const int xcd = lin & 7, idx = lin >> 3;
  const int bx = xcd * 4 + (idx & 3), by = idx >> 2;

  const int srow   = tid >> 3;
  const int schunk = ((tid & 7) ^ (srow & 7)) * 8;
  const unsigned short* Asrc = A  + (size_t)(by * 256 + srow) * HD + schunk;
  const unsigned short* Bsrc = Bw + (size_t)(bx * 256 + srow) * HD + schunk;

  f32x4 acc[2][2][4][2] = {};
  bf16x8 a[4][2], b0[2][2], b1[2][2];

#define BARX() __builtin_amdgcn_s_barrier()
#define LGKM0() asm volatile("s_waitcnt lgkmcnt(0)" ::: "memory")
#define READ_A(BUF, HALF)                                                      \
  {                                                                            \
    const unsigned short* rgA = &smA[BUF][HALF][0];                            \
    _Pragma("unroll")                                                          \
    for (int i = 0; i < 4; ++i) {                                              \
      const int r = wm * 64 + i * 16 + l16;                                    \
      const int s = r & 7;                                                     \
      a[i][0] = *(const bf16x8*)(rgA + r * 64 + ((q ^ s) << 3));               \
      a[i][1] = *(const bf16x8*)(rgA + r * 64 + (((4 + q) ^ s) << 3));         \
    }                                                                          \
  }
#define READ_B(BUF, HALF, DST)                                                 \
  {                                                                            \
    const unsigned short* rgB = &smB[BUF][HALF][0];                            \
    _Pragma("unroll")                                                          \
    for (int j = 0; j < 2; ++j) {                                              \
      const int r = wn * 32 + j * 16 + l16;                                    \
      const int s = r & 7;                                                     \
      DST[j][0] = *(const bf16x8*)(rgB + r * 64 + ((q ^ s) << 3));             \
      DST[j][1] = *(const bf16x8*)(rgB + r * 64 + (((4 + q) ^ s) << 3));       \
    }                                                                          \
  }
#define MFMA_Q(QA, QB, BB)                                                     \
  __builtin_amdgcn_s_setprio(1);                                               \
  _Pragma("unroll")                                                            \
  for (int i = 0; i < 4; ++i)                                                  \
    _Pragma("unroll")                                                          \
    for (int j = 0; j < 2; ++j) {                                              \
      acc[QA][QB][i][j] = __builtin_amdgcn_mfma_f32_16x16x32_bf16(             \
          a[i][0], BB[j][0], acc[QA][QB][i][j], 0, 0, 0);                      \
      acc[QA][QB][i][j] = __builtin_amdgcn_mfma_f32_16x16x32_bf16(             \
          a[i][1], BB[j][1], acc[QA][QB][i][j], 0, 0, 0);                      \
    }                                                                          \
  __builtin_amdgcn_s_setprio(0)

#define KITER(T0, D2, D3)                                                      \
  {                                                                            \
    const int t1 = (T0) + 1, t2 = (T0) + 2, t3 = (T0) + 3;                     \
    /* P1: reads A0,B0 (buf0); stage t1.A1 */                                  \
    READ_A(0, 0); READ_B(0, 0, b0);                                            \
    stage_half4(Asrc, 1, t1, &smA[1][1][0], wid);                              \
    asm volatile("s_waitcnt lgkmcnt(8)" ::: "memory");                         \
    BARX(); LGKM0(); MFMA_Q(0, 0, b0); BARX();                                 \
    /* P2: reads B1 (buf0); stage t2.A0 */                                     \
    READ_B(0, 1, b1);                                                          \
    if (D2) stage_half4(Asrc, 0, t2, &smA[0][0][0], wid);                      \
    BARX(); LGKM0(); MFMA_Q(0, 1, b1); BARX();                                 \
    /* P3: reads A1 (buf0); stage t2.B0 */                                     \
    READ_A(0, 1);                                                              \
    if (D2) stage_half4(Bsrc, 0, t2, &smB[0][0][0], wid);                      \
    BARX(); LGKM0(); MFMA_Q(1, 0, b0); BARX();                                 \
    /* P4: stage t2.B1; vmcnt(6) retires t1 */                                 \
    if (D2) {                                                                  \
      stage_half4(Bsrc, 1, t2, &smB[0][1][0], wid);                            \
      asm volatile("s_waitcnt vmcnt(6)" ::: "memory");                         \
    } else {                                                                   \
      asm volatile("s_waitcnt vmcnt(0)" ::: "memory");                         \
    }                                                                          \
    BARX(); MFMA_Q(1, 1, b1); BARX();                                          \
    /* P5: reads A0,B0 (buf1); stage t2.A1 */                                  \
    READ_A(1, 0); READ_B(1, 0, b0);                                            \
    if (D2) stage_half4(Asrc, 1, t2, &smA[0][1][0], wid);                      \
    asm volatile("s_waitcnt lgkmcnt(8)" ::: "memory");                         \
    BARX(); LGKM0(); MFMA_Q(0, 0, b0); BARX();                                 \
    /* P6: reads B1 (buf1); stage t3.A0 */                                     \
    READ_B(1, 1, b1);                                                          \
    if (D3) stage_half4(Asrc, 0, t3, &smA[1][0][0], wid);                      \
    BARX(); LGKM0(); MFMA_Q(0, 1, b1); BARX();                                 \
    /* P7: reads A1 (buf1); stage t3.B0 */                                     \
    READ_A(1, 1);                                                              \
    if (D3) stage_half4(Bsrc, 0, t3, &smB[1][0][0], wid);                      \
    BARX(); LGKM0(); MFMA_Q(1, 0, b0); BARX();                                 \
    /* P8: stage t3.B1; vmcnt(6) retires t2 */                                 \
    if (D3) {                                                                  \
      stage_half4(Bsrc, 1, t3, &smB[1][1][0], wid);                            \
      asm volatile("s_waitcnt vmcnt(6)" ::: "memory");                         \
    } else {                                                                   \
      asm volatile("s_waitcnt vmcnt(0)" ::: "memory");                         \
    }                                                                          \
    BARX(); MFMA_Q(1, 1, b1); BARX();                                          \
  }

  // prologue: t0 {A0,B0,B1,A1} + t1 {A0,B0,B1}; vmcnt(6) -> t0 resident
  stage_half4(Asrc, 0, 0, &smA[0][0][0], wid);
  stage_half4(Bsrc, 0, 0, &smB[0][0][0], wid);
  stage_half4(Bsrc, 1, 0, &smB[0][1][0], wid);
  stage_half4(Asrc, 1, 0, &smA[0][1][0], wid);
  stage_half4(Asrc, 0, 1, &smA[1][0][0], wid);
  stage_half4(Bsrc, 0, 1, &smB[1][0][0], wid);
  stage_half4(Bsrc, 1, 1, &smB[1][1][0], wid);
  asm volatile("s_waitcnt vmcnt(6)" ::: "memory");
  BARX();

#pragma unroll 1
  for (int it = 0; it < (NT >> 1) - 1; ++it) KITER(2 * it, true, true);
  KITER(NT - 2, false, false);   // peeled: t2,t3 >= NT

#undef KITER
#undef MFMA_Q
#undef READ_B
#undef READ_A
#undef LGKM0
#undef BARX

  // epilogue: C/D layout col = lane&15, row = q*4 + reg (m89-verified)
  const int m0 = by * 256 + wm * 64 + q * 4;
  const int n0 = bx * 256 + wn * 32 + l16;
#pragma unroll
  for (int qa = 0; qa < 2; ++qa)
#pragma unroll
    for (int qb = 0; qb < 2; ++qb)
#pragma unroll
      for (int i = 0; i < 4; ++i)
#pragma unroll
        for (int j = 0; j < 2; ++j)
#pragma unroll
          for (int r = 0; r < 4; ++r) {
            const int m = m0 + qa * 128 + i * 16 + r;
            const int n = n0 + qb * 128 + j * 16;
            float v = acc[qa][qb][i][j][r];
            if (MODE == 2) {
              gate_bf[(size_t)m * NN + n] = f2bf(1.0f / (1.0f + expf(-v)));
            } else {  // MODE 1: n<HD uniform per (bx,qb) since 256 | HD
              if (n < HD) {
                float g = 0.5f * v * (1.0f + erff(v * 0.70710678118654752f));
                gate_bf[(size_t)m * HD + n] = f2bf(g);
              } else {
                xrec[(size_t)m * HD + (n - HD)] = v;
              }
            }
          }
}

// ---------------------------------------------------------------- conv fuse
__global__ void conv_fuse(const float* __restrict__ cs, const float* xr,
                          const float4* __restrict__ cw, const float* __restrict__ cb,
                          float* __restrict__ ncs, float* xc_out,
                          unsigned short* __restrict__ xc_bf) {
  int t = blockIdx.x * 256 + threadIdx.x;       // t < BSZ*HD
  int h = t & (HD - 1);
  float c0 = cs[3 * t + 0];
  float c1 = cs[3 * t + 1];
  float c2 = cs[3 * t + 2];
  float xv = xr[t];
  float4 w = cw[h];
  float v = fmaf(c0, w.x, fmaf(c1, w.y, fmaf(c2, w.z, fmaf(xv, w.w, cb[h]))));
  ncs[3 * t + 0] = c1;
  ncs[3 * t + 1] = c2;
  ncs[3 * t + 2] = xv;
  xc_out[t] = v;
  xc_bf[t] = f2bf(v);
}

// ---------------------------------------------------------------- rglru fuse
__global__ void rglru_fuse(const unsigned short* __restrict__ gates_bf,
                           const float* __restrict__ av,
                           const float* __restrict__ rs, const float* __restrict__ xc,
                           const unsigned short* __restrict__ gbf,
                           float* __restrict__ nrs, unsigned short* __restrict__ gated) {
  int t = blockIdx.x * 256 + threadIdx.x;       // t < BSZ*HD
  int h = t & (HD - 1);
  int b = t >> 12;
  float it = bf2f(gates_bf[(size_t)b * (2 * HD) + h]);
  float rt = bf2f(gates_bf[(size_t)b * (2 * HD) + HD + h]);
  float at = expf(8.0f * rt * logf(av[h]));
  float mult = sqrtf(fmaxf(0.0f, 1.0f - at * at));
  float x = xc[t];
  float nv = fmaf(rs[t], at, mult * (it * x));
  nrs[t] = nv;
  gated[t] = f2bf(bf2f(gbf[t]) * nv);
}

// ---------------------------------------------------------------- launch
extern "C" void kernel_launch(void* const* d_in, const int* in_sizes, int n_in,
                              void* d_out, int out_size, void* d_ws, size_t ws_size,
                              hipStream_t stream) {
  const float* x  = (const float*)d_in[0];
  const float* cs = (const float*)d_in[1];
  const float* rs = (const float*)d_in[2];
  const float* wf = (const float*)d_in[3];
  const float* cw = (const float*)d_in[4];
  const float* cb = (const float*)d_in[5];
  const float* wg = (const float*)d_in[6];
  const float* av = (const float*)d_in[7];
  const float* wo = (const float*)d_in[8];

  float* out = (float*)d_out;                        // (B,H)
  float* ncs = out + (size_t)BSZ * HD;               // (B,H,3)
  float* nrs = out + (size_t)BSZ * HD * 4;           // (B,H)

  char* ws = (char*)d_ws;
  unsigned short* x_bf   = (unsigned short*)(ws);
  unsigned short* wf_bf  = (unsigned short*)(ws + (size_t)(16u)  * 1048576u);
  unsigned short* wg_bf  = (unsigned short*)(ws + (size_t)(80u)  * 1048576u);
  unsigned short* wo_bf  = (unsigned short*)(ws + (size_t)(144u) * 1048576u);
  unsigned short* gatebf = (unsigned short*)(ws + (size_t)(176u) * 1048576u);
  float*          xrc    = (float*)         (ws + (size_t)(192u) * 1048576u);
  unsigned short* xc_bf  = (unsigned short*)(ws + (size_t)(224u) * 1048576u);
  unsigned short* gates_bf = wf_bf;                  // alias: wf_bf dead after GEMM1
  unsigned short* gated    = x_bf;                   // alias: x_bf dead after GEMM1

  // 1) all bf16 conversions, one launch
  constexpr int CVT_BLKS = (BSZ * HD / 4 + 2 * (2 * HD * HD / 4) + HD * HD / 4) / 256;
  cvt_all<<<CVT_BLKS, 256, 0, stream>>>(
      (const float4*)x, (const float4*)wf, (const float4*)wg, (const float4*)wo,
      (ushort4*)x_bf, (ushort4*)wf_bf, (ushort4*)wg_bf, (ushort4*)wo_bf);

  // 2) fused = x @ w_fused^T  (256^2 8-phase; grid 32x8 = 256 blocks)
  dim3 g256(2 * HD / 256, BSZ / 256);
  gemm256_k<<<g256, 512, 0, stream>>>(x_bf, wf_bf, gatebf, xrc, 1);
  // 3) conv + state shift
  conv_fuse<<<(BSZ * HD) / 256, 256, 0, stream>>>(cs, xrc, (const float4*)cw, cb, ncs, xrc, xc_bf);
  // 4) gates = sigmoid(x_conv @ w_gates^T) -> bf16
  gemm256_k<<<g256, 512, 0, stream>>>(xc_bf, wg_bf, gates_bf, nullptr, 2);
  // 5) rglru recurrence + gated = gate * new_state
  rglru_fuse<<<(BSZ * HD) / 256, 256, 0, stream>>>(gates_bf, av, rs, xrc, gatebf, nrs, gated);
  // 6) out = gated @ w_out^T (128^2 kernel: 512 blocks keeps all CUs busy)
  dim3 g3(HD / BN, BSZ / BM);
  gemm_bt<0, HD, HD><<<g3, dim3(256), 0, stream>>>(gated, wo_bf, out, nullptr, nullptr);
}